// Round 1
// baseline (13592.447 us; speedup 1.0000x reference)
//
#include <hip/hip_runtime.h>

// ---------------------------------------------------------------------------
// dLSTM: 2-layer LSTM (B=32, H=2048) + projected feedback, seq_len=128.
// Strategy: bf16-convert all weights once into d_ws (142 MB -> L3-resident),
// then ONE persistent kernel (256 wgs x 512 thr) runs the whole recurrence
// with hand-rolled device-scope grid barriers. Gates via mfma_16x16x32_bf16,
// weights streamed global->VGPR as B-fragments, LSTM cell fused in epilogue.
// Feedback projection x = h1 @ W_out^T folded as a third (small) phase.
// ---------------------------------------------------------------------------

typedef __attribute__((ext_vector_type(8))) short short8;
typedef __attribute__((ext_vector_type(4))) short short4v;
typedef __attribute__((ext_vector_type(4))) float f32x4;

#define MFMA16(a, b, c) __builtin_amdgcn_mfma_f32_16x16x32_bf16((a), (b), (c), 0, 0, 0)

static constexpr int BATCH = 32;
static constexpr int HID = 2048;
static constexpr int NWG = 256;
static constexpr int NTHR = 512;   // 8 waves

__device__ __forceinline__ unsigned short f2bf(float x) {
  unsigned u = __float_as_uint(x);
  u += 0x7FFFu + ((u >> 16) & 1u);   // RNE
  return (unsigned short)(u >> 16);
}

__device__ __forceinline__ float sigm(float x) { return 1.f / (1.f + __expf(-x)); }
__device__ __forceinline__ float tanh_(float x) {
  float e = __expf(2.f * x);
  return 1.f - 2.f / (e + 1.f);      // saturates correctly at +-inf, no NaN
}

// ---------------- weight conversion f32 -> bf16 ----------------------------
__global__ void cvt_bf16_k(const float* __restrict__ s, unsigned short* __restrict__ d,
                           long n4) {
  long i = blockIdx.x * (long)blockDim.x + threadIdx.x;
  long st = (long)gridDim.x * blockDim.x;
  for (; i < n4; i += st) {
    float4 v = ((const float4*)s)[i];
    short4v o;
    o.x = (short)f2bf(v.x); o.y = (short)f2bf(v.y);
    o.z = (short)f2bf(v.z); o.w = (short)f2bf(v.w);
    ((short4v*)d)[i] = o;
  }
}

// ---------------- per-call state init --------------------------------------
__global__ void init_k(const float* __restrict__ h0, const float* __restrict__ c0,
                       unsigned short* xbf, unsigned short* h0bf, unsigned short* h1bf,
                       float* c0f, float* c1f, unsigned* bar) {
  int i = blockIdx.x * blockDim.x + threadIdx.x;
  if (i < BATCH * HID) {
    xbf[i] = 0;                       // x(t=0) = zeros
    h0bf[i] = f2bf(h0[i]);            // layer 0 h  (parity-0 buffer)
    h1bf[i] = f2bf(h0[BATCH * HID + i]);
    c0f[i] = c0[i];
    c1f[i] = c0[BATCH * HID + i];
  }
  if (i == 0) { bar[0] = 0u; bar[1] = 0u; }
}

// ---------------- device-scope grid barrier --------------------------------
__device__ __forceinline__ void grid_barrier(unsigned* bar) {
  __syncthreads();
  if (threadIdx.x == 0) {
    unsigned g = __hip_atomic_load(&bar[1], __ATOMIC_RELAXED, __HIP_MEMORY_SCOPE_AGENT);
    unsigned a = __hip_atomic_fetch_add(&bar[0], 1u, __ATOMIC_ACQ_REL, __HIP_MEMORY_SCOPE_AGENT);
    if (a == NWG - 1) {
      __hip_atomic_store(&bar[0], 0u, __ATOMIC_RELAXED, __HIP_MEMORY_SCOPE_AGENT);
      __hip_atomic_store(&bar[1], g + 1u, __ATOMIC_RELEASE, __HIP_MEMORY_SCOPE_AGENT);
    } else {
      while (__hip_atomic_load(&bar[1], __ATOMIC_RELAXED, __HIP_MEMORY_SCOPE_AGENT) == g) {
        __builtin_amdgcn_s_sleep(1);
      }
      (void)__hip_atomic_load(&bar[1], __ATOMIC_ACQUIRE, __HIP_MEMORY_SCOPE_AGENT);
    }
  }
  __syncthreads();
}

// ---------------- one LSTM layer: gates matmul + cell, fused ---------------
// wg owns 8 h-columns (j0..j0+7): gate rows {j0+c, 2048+j0+c, 4096+j0+c, 6144+j0+c}.
// N-tile0 = 8 i-rows ++ 8 f-rows ; N-tile1 = 8 g-rows ++ 8 o-rows (= tile0 rows + 4096).
// 8 waves split K=4096 (2048 input-part A1/W1 + 2048 recurrent A2/W2) into 8x512.
__device__ __forceinline__ void layer_phase(
    int wg, int tid,
    const unsigned short* __restrict__ A1, const unsigned short* __restrict__ A2,
    const unsigned short* __restrict__ W1, const unsigned short* __restrict__ W2,
    const float* __restrict__ bi, const float* __restrict__ bh,
    float* __restrict__ c, unsigned short* __restrict__ hout,
    float* __restrict__ outp,
    float (*red)[4][64][4]) {
  const int wv = tid >> 6, lane = tid & 63;
  const int nn = lane & 15, kb = (lane >> 4) << 3;
  const int j0 = wg * 8;
  const int part = wv >> 2;                 // 0: input part, 1: recurrent part
  const int k0 = (wv & 3) * 512;            // K-eighth
  const unsigned short* A = part ? A2 : A1;
  const unsigned short* W = part ? W2 : W1;
  const int r0 = (nn < 8) ? (j0 + nn) : (2048 + j0 + (nn - 8));

  const short8* pA0 = (const short8*)(A + (size_t)nn * HID + k0 + kb);
  const short8* pA1 = (const short8*)(A + (size_t)(nn + 16) * HID + k0 + kb);
  const short8* pB0 = (const short8*)(W + (size_t)r0 * HID + k0 + kb);
  const short8* pB1 = (const short8*)(W + (size_t)(r0 + 4096) * HID + k0 + kb);

  f32x4 acc00 = {0.f, 0.f, 0.f, 0.f}, acc01 = acc00, acc10 = acc00, acc11 = acc00;

  // depth-3 software pipeline, fully unrolled (static slot indices)
  short8 A0s[4], A1s[4], B0s[4], B1s[4];
#pragma unroll
  for (int p = 0; p < 3; ++p) {
    A0s[p] = pA0[4 * p]; A1s[p] = pA1[4 * p];
    B0s[p] = pB0[4 * p]; B1s[p] = pB1[4 * p];
  }
#pragma unroll
  for (int it = 0; it < 16; ++it) {
    const int cs = it & 3;
    const int ps = (it + 3) & 3;
    if (it < 13) {
      A0s[ps] = pA0[4 * (it + 3)]; A1s[ps] = pA1[4 * (it + 3)];
      B0s[ps] = pB0[4 * (it + 3)]; B1s[ps] = pB1[4 * (it + 3)];
    }
    acc00 = MFMA16(A0s[cs], B0s[cs], acc00);
    acc01 = MFMA16(A1s[cs], B0s[cs], acc01);
    acc10 = MFMA16(A0s[cs], B1s[cs], acc10);
    acc11 = MFMA16(A1s[cs], B1s[cs], acc11);
  }

  *(f32x4*)&red[wv][0][lane][0] = acc00;   // tile0, M-half0
  *(f32x4*)&red[wv][1][lane][0] = acc01;   // tile0, M-half1
  *(f32x4*)&red[wv][2][lane][0] = acc10;   // tile1, M-half0
  *(f32x4*)&red[wv][3][lane][0] = acc11;   // tile1, M-half1
  __syncthreads();

  if (tid < 256) {
    const int b = tid >> 3, cc = tid & 7;
    const int m = b >> 4, br = b & 15;
    const int reg = br & 3, lbase = (br >> 2) << 4;
    float gi = 0.f, gf = 0.f, gg = 0.f, go = 0.f;
#pragma unroll
    for (int w = 0; w < 8; ++w) {
      gi += red[w][m][lbase + cc][reg];
      gf += red[w][m][lbase + cc + 8][reg];
      gg += red[w][2 + m][lbase + cc][reg];
      go += red[w][2 + m][lbase + cc + 8][reg];
    }
    const int col = j0 + cc;
    gi += bi[col] + bh[col];
    gf += bi[2048 + col] + bh[2048 + col];
    gg += bi[4096 + col] + bh[4096 + col];
    go += bi[6144 + col] + bh[6144 + col];
    const float iv = sigm(gi);
    const float fv = sigm(gf);
    const float gv = tanh_(gg);
    const float ov = sigm(go);
    const float cold = c[b * HID + col];
    const float cnew = fv * cold + iv * gv;
    const float hnew = ov * tanh_(cnew);
    c[b * HID + col] = cnew;
    hout[b * HID + col] = f2bf(hnew);
    if (outp) outp[b * HID + col] = hnew;
  }
}

// ---------------- feedback projection: x = h1_new @ W_out^T + b_out --------
// 128 active wgs, each owns 16 x-columns; 8 waves split K=2048 into 8x256.
__device__ __forceinline__ void proj_phase(
    int wg, int tid,
    const unsigned short* __restrict__ Anew,
    const unsigned short* __restrict__ Wo,
    const float* __restrict__ bout,
    unsigned short* __restrict__ xbf,
    float (*red)[4][64][4]) {
  const int wv = tid >> 6, lane = tid & 63;
  const int nn = lane & 15, kb = (lane >> 4) << 3;
  const int m0 = wg * 16;
  const int k0 = wv * 256;

  const short8* pA0 = (const short8*)(Anew + (size_t)nn * HID + k0 + kb);
  const short8* pA1 = (const short8*)(Anew + (size_t)(nn + 16) * HID + k0 + kb);
  const short8* pB = (const short8*)(Wo + (size_t)(m0 + nn) * HID + k0 + kb);

  f32x4 acc0 = {0.f, 0.f, 0.f, 0.f}, acc1 = acc0;
#pragma unroll
  for (int it = 0; it < 8; ++it) {
    short8 a0 = pA0[4 * it], a1 = pA1[4 * it], bb = pB[4 * it];
    acc0 = MFMA16(a0, bb, acc0);
    acc1 = MFMA16(a1, bb, acc1);
  }
  *(f32x4*)&red[wv][0][lane][0] = acc0;
  *(f32x4*)&red[wv][1][lane][0] = acc1;
  __syncthreads();

  const int b = tid >> 4, col = tid & 15;   // 512 threads, one element each
  const int m = b >> 4, br = b & 15;
  const int reg = br & 3, lane_r = ((br >> 2) << 4) | col;
  float x = 0.f;
#pragma unroll
  for (int w = 0; w < 8; ++w) x += red[w][m][lane_r][reg];
  x += bout[m0 + col];
  xbf[b * HID + m0 + col] = f2bf(x);
}

// ---------------- persistent driver ----------------------------------------
__global__ __launch_bounds__(NTHR, 1) void lstm_persist(
    const unsigned short* __restrict__ Wihb,   // [2][8192][2048] bf16
    const unsigned short* __restrict__ Whhb,   // [2][8192][2048] bf16
    const unsigned short* __restrict__ Woutb,  // [2048][2048] bf16
    const float* __restrict__ bih, const float* __restrict__ bhh,
    const float* __restrict__ bout,
    unsigned short* xbf,
    unsigned short* h0bf,   // [2][32][2048] ping-pong
    unsigned short* h1bf,   // [2][32][2048] ping-pong
    float* c0f, float* c1f,
    float* __restrict__ out, int T, unsigned* bar) {
  __shared__ float red[8][4][64][4];   // 32 KiB
  const int wg = blockIdx.x, tid = threadIdx.x;
  const size_t BH = (size_t)BATCH * HID;
  const size_t WL = (size_t)8192 * 2048;

  for (int t = 0; t < T; ++t) {
    const int par = t & 1;
    // layer 0: inputs x(t), h0[par] -> h0[par^1], c0
    layer_phase(wg, tid, xbf, h0bf + par * BH,
                Wihb, Whhb, bih, bhh,
                c0f, h0bf + (par ^ 1) * BH, (float*)nullptr, red);
    grid_barrier(bar);
    // layer 1: inputs h0_new, h1[par] -> h1[par^1], c1 ; writes out[t]
    layer_phase(wg, tid, h0bf + (par ^ 1) * BH, h1bf + par * BH,
                Wihb + WL, Whhb + WL, bih + 8192, bhh + 8192,
                c1f, h1bf + (par ^ 1) * BH, out + (size_t)t * BH, red);
    grid_barrier(bar);
    // projection: x(t+1) = h1_new @ W_out^T + b_out
    if (wg < 128) proj_phase(wg, tid, h1bf + (par ^ 1) * BH, Woutb, bout, xbf, red);
    grid_barrier(bar);
  }
}

// ---------------------------------------------------------------------------
extern "C" void kernel_launch(void* const* d_in, const int* in_sizes, int n_in,
                              void* d_out, int out_size, void* d_ws, size_t ws_size,
                              hipStream_t stream) {
  const float* h0 = (const float*)d_in[0];
  const float* c0 = (const float*)d_in[1];
  const float* Wih = (const float*)d_in[2];
  const float* Whh = (const float*)d_in[3];
  const float* bih = (const float*)d_in[4];
  const float* bhh = (const float*)d_in[5];
  const float* Wout = (const float*)d_in[6];
  const float* bout = (const float*)d_in[7];
  float* out = (float*)d_out;
  const int T = out_size / (BATCH * HID);

  // workspace layout (bytes total ~143.8 MB)
  unsigned short* Wihb = (unsigned short*)d_ws;             // 33,554,432 elems
  unsigned short* Whhb = Wihb + (size_t)33554432;           // 33,554,432
  unsigned short* Woutb = Whhb + (size_t)33554432;          // 4,194,304
  unsigned short* xbf = Woutb + (size_t)4194304;            // 65,536
  unsigned short* h0bf = xbf + 65536;                       // 131,072 (x2 ping-pong)
  unsigned short* h1bf = h0bf + 131072;                     // 131,072
  float* c0f = (float*)(h1bf + 131072);                     // 65,536 f32
  float* c1f = c0f + 65536;                                 // 65,536 f32
  unsigned* bar = (unsigned*)(c1f + 65536);                 // 2 u32

  cvt_bf16_k<<<4096, 256, 0, stream>>>(Wih, Wihb, (long)(2LL * 8192 * 2048 / 4));
  cvt_bf16_k<<<4096, 256, 0, stream>>>(Whh, Whhb, (long)(2LL * 8192 * 2048 / 4));
  cvt_bf16_k<<<1024, 256, 0, stream>>>(Wout, Woutb, (long)(2048LL * 2048 / 4));
  init_k<<<256, 256, 0, stream>>>(h0, c0, xbf, h0bf, h1bf, c0f, c1f, bar);
  lstm_persist<<<NWG, NTHR, 0, stream>>>(Wihb, Whhb, Woutb, bih, bhh, bout,
                                         xbf, h0bf, h1bf, c0f, c1f, out, T, bar);
}

// Round 2
// 8138.345 us; speedup vs baseline: 1.6702x; 1.6702x over previous
//
#include <hip/hip_runtime.h>

// ---------------------------------------------------------------------------
// dLSTM: 2-layer LSTM (B=32, H=2048) + projected feedback, seq_len=128.
// bf16 weights in d_ws (142 MB -> L3-resident); ONE persistent kernel
// (256 wgs x 512 thr) runs the recurrence. R2 change: hierarchical RELAXED
// grid barrier (8 groups of 32 -> master -> epoch) with ONE release fence
// before arrival + ONE acquire fence after release, per wg. The R1 barrier's
// 256 serialized agent-scope ACQ_REL RMWs (each with L2 wb/inv) cost ~32us
// per barrier x 384 barriers = ~12ms of the 13.6ms total.
// ---------------------------------------------------------------------------

typedef __attribute__((ext_vector_type(8))) short short8;
typedef __attribute__((ext_vector_type(4))) short short4v;
typedef __attribute__((ext_vector_type(4))) float f32x4;

#define MFMA16(a, b, c) __builtin_amdgcn_mfma_f32_16x16x32_bf16((a), (b), (c), 0, 0, 0)

static constexpr int BATCH = 32;
static constexpr int HID = 2048;
static constexpr int NWG = 256;
static constexpr int NTHR = 512;   // 8 waves

__device__ __forceinline__ unsigned short f2bf(float x) {
  unsigned u = __float_as_uint(x);
  u += 0x7FFFu + ((u >> 16) & 1u);   // RNE
  return (unsigned short)(u >> 16);
}

__device__ __forceinline__ float sigm(float x) { return 1.f / (1.f + __expf(-x)); }
__device__ __forceinline__ float tanh_(float x) {
  float e = __expf(2.f * x);
  return 1.f - 2.f / (e + 1.f);      // saturates correctly at +-inf, no NaN
}

// ---------------- weight conversion f32 -> bf16 ----------------------------
__global__ void cvt_bf16_k(const float* __restrict__ s, unsigned short* __restrict__ d,
                           long n4) {
  long i = blockIdx.x * (long)blockDim.x + threadIdx.x;
  long st = (long)gridDim.x * blockDim.x;
  for (; i < n4; i += st) {
    float4 v = ((const float4*)s)[i];
    short4v o;
    o.x = (short)f2bf(v.x); o.y = (short)f2bf(v.y);
    o.z = (short)f2bf(v.z); o.w = (short)f2bf(v.w);
    ((short4v*)d)[i] = o;
  }
}

// ---------------- per-call state init --------------------------------------
__global__ void init_k(const float* __restrict__ h0, const float* __restrict__ c0,
                       unsigned short* xbf, unsigned short* h0bf, unsigned short* h1bf,
                       float* c0f, float* c1f, unsigned* bar) {
  int i = blockIdx.x * blockDim.x + threadIdx.x;
  if (i < BATCH * HID) {
    xbf[i] = 0;                       // x(t=0) = zeros
    h0bf[i] = f2bf(h0[i]);            // layer 0 h  (parity-0 buffer)
    h1bf[i] = f2bf(h0[BATCH * HID + i]);
    c0f[i] = c0[i];
    c1f[i] = c0[BATCH * HID + i];
  }
  if (i < 320) bar[i] = 0u;           // group cnts, master, epoch
}

// ---------------- hierarchical device-scope grid barrier -------------------
// Monotonic counters, RELAXED RMWs (no per-arrival cache maintenance).
// bar[g*32] g=0..7 : group counters (128B apart)
// bar[256]          : master counter
// bar[288]          : epoch
__device__ __forceinline__ void grid_barrier(unsigned* bar, int bno) {
  __syncthreads();   // all waves' stores issued (vmcnt drained at s_barrier)
  if (threadIdx.x == 0) {
    __builtin_amdgcn_fence(__ATOMIC_RELEASE, "agent");   // flush dirty L2 (h/x/out)
    const int g = blockIdx.x >> 5;
    unsigned a = __hip_atomic_fetch_add(&bar[g * 32], 1u,
                                        __ATOMIC_RELAXED, __HIP_MEMORY_SCOPE_AGENT);
    if (a == (unsigned)(32 * bno - 1)) {
      unsigned m = __hip_atomic_fetch_add(&bar[256], 1u,
                                          __ATOMIC_RELAXED, __HIP_MEMORY_SCOPE_AGENT);
      if (m == (unsigned)(8 * bno - 1)) {
        __hip_atomic_store(&bar[288], (unsigned)bno,
                           __ATOMIC_RELAXED, __HIP_MEMORY_SCOPE_AGENT);
      }
    }
    while (__hip_atomic_load(&bar[288], __ATOMIC_RELAXED,
                             __HIP_MEMORY_SCOPE_AGENT) < (unsigned)bno) {
      __builtin_amdgcn_s_sleep(2);
    }
    __builtin_amdgcn_fence(__ATOMIC_ACQUIRE, "agent");   // inv L1/L2 -> fresh reads
  }
  __syncthreads();
}

// ---------------- one LSTM layer: gates matmul + cell, fused ---------------
// wg owns 8 h-columns (j0..j0+7): gate rows {j0+c, 2048+j0+c, 4096+j0+c, 6144+j0+c}.
// N-tile0 = 8 i-rows ++ 8 f-rows ; N-tile1 = 8 g-rows ++ 8 o-rows (tile0 rows + 4096).
// 8 waves split K=4096 (2048 input part A1/W1 + 2048 recurrent A2/W2) into 8x512.
__device__ __forceinline__ void layer_phase(
    int wg, int tid,
    const unsigned short* __restrict__ A1, const unsigned short* __restrict__ A2,
    const unsigned short* __restrict__ W1, const unsigned short* __restrict__ W2,
    const float* __restrict__ bi, const float* __restrict__ bh,
    float* __restrict__ c, unsigned short* __restrict__ hout,
    float* __restrict__ outp,
    float (*red)[4][64][4]) {
  const int wv = tid >> 6, lane = tid & 63;
  const int nn = lane & 15, kb = (lane >> 4) << 3;
  const int j0 = wg * 8;
  const int part = wv >> 2;                 // 0: input part, 1: recurrent part
  const int k0 = (wv & 3) * 512;            // K-eighth
  const unsigned short* A = part ? A2 : A1;
  const unsigned short* W = part ? W2 : W1;
  const int r0 = (nn < 8) ? (j0 + nn) : (2048 + j0 + (nn - 8));

  const short8* pA0 = (const short8*)(A + (size_t)nn * HID + k0 + kb);
  const short8* pA1 = (const short8*)(A + (size_t)(nn + 16) * HID + k0 + kb);
  const short8* pB0 = (const short8*)(W + (size_t)r0 * HID + k0 + kb);
  const short8* pB1 = (const short8*)(W + (size_t)(r0 + 4096) * HID + k0 + kb);

  f32x4 acc00 = {0.f, 0.f, 0.f, 0.f}, acc01 = acc00, acc10 = acc00, acc11 = acc00;

  // depth-3 software pipeline, fully unrolled (static slot indices)
  short8 A0s[4], A1s[4], B0s[4], B1s[4];
#pragma unroll
  for (int p = 0; p < 3; ++p) {
    A0s[p] = pA0[4 * p]; A1s[p] = pA1[4 * p];
    B0s[p] = pB0[4 * p]; B1s[p] = pB1[4 * p];
  }
#pragma unroll
  for (int it = 0; it < 16; ++it) {
    const int cs = it & 3;
    const int ps = (it + 3) & 3;
    if (it < 13) {
      A0s[ps] = pA0[4 * (it + 3)]; A1s[ps] = pA1[4 * (it + 3)];
      B0s[ps] = pB0[4 * (it + 3)]; B1s[ps] = pB1[4 * (it + 3)];
    }
    acc00 = MFMA16(A0s[cs], B0s[cs], acc00);
    acc01 = MFMA16(A1s[cs], B0s[cs], acc01);
    acc10 = MFMA16(A0s[cs], B1s[cs], acc10);
    acc11 = MFMA16(A1s[cs], B1s[cs], acc11);
  }

  *(f32x4*)&red[wv][0][lane][0] = acc00;   // tile0, M-half0
  *(f32x4*)&red[wv][1][lane][0] = acc01;   // tile0, M-half1
  *(f32x4*)&red[wv][2][lane][0] = acc10;   // tile1, M-half0
  *(f32x4*)&red[wv][3][lane][0] = acc11;   // tile1, M-half1
  __syncthreads();

  if (tid < 256) {
    const int b = tid >> 3, cc = tid & 7;
    const int m = b >> 4, br = b & 15;
    const int reg = br & 3, lbase = (br >> 2) << 4;
    float gi = 0.f, gf = 0.f, gg = 0.f, go = 0.f;
#pragma unroll
    for (int w = 0; w < 8; ++w) {
      gi += red[w][m][lbase + cc][reg];
      gf += red[w][m][lbase + cc + 8][reg];
      gg += red[w][2 + m][lbase + cc][reg];
      go += red[w][2 + m][lbase + cc + 8][reg];
    }
    const int col = j0 + cc;
    gi += bi[col] + bh[col];
    gf += bi[2048 + col] + bh[2048 + col];
    gg += bi[4096 + col] + bh[4096 + col];
    go += bi[6144 + col] + bh[6144 + col];
    const float iv = sigm(gi);
    const float fv = sigm(gf);
    const float gv = tanh_(gg);
    const float ov = sigm(go);
    const float cold = c[b * HID + col];
    const float cnew = fv * cold + iv * gv;
    const float hnew = ov * tanh_(cnew);
    c[b * HID + col] = cnew;
    hout[b * HID + col] = f2bf(hnew);
    if (outp) outp[b * HID + col] = hnew;
  }
}

// ---------------- feedback projection: x = h1_new @ W_out^T + b_out --------
// 128 active wgs, each owns 16 x-columns; 8 waves split K=2048 into 8x256.
__device__ __forceinline__ void proj_phase(
    int wg, int tid,
    const unsigned short* __restrict__ Anew,
    const unsigned short* __restrict__ Wo,
    const float* __restrict__ bout,
    unsigned short* __restrict__ xbf,
    float (*red)[4][64][4]) {
  const int wv = tid >> 6, lane = tid & 63;
  const int nn = lane & 15, kb = (lane >> 4) << 3;
  const int m0 = wg * 16;
  const int k0 = wv * 256;

  const short8* pA0 = (const short8*)(Anew + (size_t)nn * HID + k0 + kb);
  const short8* pA1 = (const short8*)(Anew + (size_t)(nn + 16) * HID + k0 + kb);
  const short8* pB = (const short8*)(Wo + (size_t)(m0 + nn) * HID + k0 + kb);

  f32x4 acc0 = {0.f, 0.f, 0.f, 0.f}, acc1 = acc0;
#pragma unroll
  for (int it = 0; it < 8; ++it) {
    short8 a0 = pA0[4 * it], a1 = pA1[4 * it], bb = pB[4 * it];
    acc0 = MFMA16(a0, bb, acc0);
    acc1 = MFMA16(a1, bb, acc1);
  }
  *(f32x4*)&red[wv][0][lane][0] = acc0;
  *(f32x4*)&red[wv][1][lane][0] = acc1;
  __syncthreads();

  const int b = tid >> 4, col = tid & 15;   // 512 threads, one element each
  const int m = b >> 4, br = b & 15;
  const int reg = br & 3, lane_r = ((br >> 2) << 4) | col;
  float x = 0.f;
#pragma unroll
  for (int w = 0; w < 8; ++w) x += red[w][m][lane_r][reg];
  x += bout[m0 + col];
  xbf[b * HID + m0 + col] = f2bf(x);
}

// ---------------- persistent driver ----------------------------------------
__global__ __launch_bounds__(NTHR, 1) void lstm_persist(
    const unsigned short* __restrict__ Wihb,   // [2][8192][2048] bf16
    const unsigned short* __restrict__ Whhb,   // [2][8192][2048] bf16
    const unsigned short* __restrict__ Woutb,  // [2048][2048] bf16
    const float* __restrict__ bih, const float* __restrict__ bhh,
    const float* __restrict__ bout,
    unsigned short* xbf,
    unsigned short* h0bf,   // [2][32][2048] ping-pong
    unsigned short* h1bf,   // [2][32][2048] ping-pong
    float* c0f, float* c1f,
    float* __restrict__ out, int T, unsigned* bar) {
  __shared__ float red[8][4][64][4];   // 32 KiB
  const int wg = blockIdx.x, tid = threadIdx.x;
  const size_t BH = (size_t)BATCH * HID;
  const size_t WL = (size_t)8192 * 2048;
  int bno = 1;

  for (int t = 0; t < T; ++t) {
    const int par = t & 1;
    // layer 0: inputs x(t), h0[par] -> h0[par^1], c0
    layer_phase(wg, tid, xbf, h0bf + par * BH,
                Wihb, Whhb, bih, bhh,
                c0f, h0bf + (par ^ 1) * BH, (float*)nullptr, red);
    grid_barrier(bar, bno++);
    // layer 1: inputs h0_new, h1[par] -> h1[par^1], c1 ; writes out[t]
    layer_phase(wg, tid, h0bf + (par ^ 1) * BH, h1bf + par * BH,
                Wihb + WL, Whhb + WL, bih + 8192, bhh + 8192,
                c1f, h1bf + (par ^ 1) * BH, out + (size_t)t * BH, red);
    grid_barrier(bar, bno++);
    // projection: x(t+1) = h1_new @ W_out^T + b_out
    if (wg < 128) proj_phase(wg, tid, h1bf + (par ^ 1) * BH, Woutb, bout, xbf, red);
    grid_barrier(bar, bno++);
  }
}

// ---------------------------------------------------------------------------
extern "C" void kernel_launch(void* const* d_in, const int* in_sizes, int n_in,
                              void* d_out, int out_size, void* d_ws, size_t ws_size,
                              hipStream_t stream) {
  const float* h0 = (const float*)d_in[0];
  const float* c0 = (const float*)d_in[1];
  const float* Wih = (const float*)d_in[2];
  const float* Whh = (const float*)d_in[3];
  const float* bih = (const float*)d_in[4];
  const float* bhh = (const float*)d_in[5];
  const float* Wout = (const float*)d_in[6];
  const float* bout = (const float*)d_in[7];
  float* out = (float*)d_out;
  const int T = out_size / (BATCH * HID);

  // workspace layout (bytes total ~143.8 MB)
  unsigned short* Wihb = (unsigned short*)d_ws;             // 33,554,432 elems
  unsigned short* Whhb = Wihb + (size_t)33554432;           // 33,554,432
  unsigned short* Woutb = Whhb + (size_t)33554432;          // 4,194,304
  unsigned short* xbf = Woutb + (size_t)4194304;            // 65,536
  unsigned short* h0bf = xbf + 65536;                       // 131,072 (x2 ping-pong)
  unsigned short* h1bf = h0bf + 131072;                     // 131,072
  float* c0f = (float*)(h1bf + 131072);                     // 65,536 f32
  float* c1f = c0f + 65536;                                 // 65,536 f32
  unsigned* bar = (unsigned*)(c1f + 65536);                 // 320 u32

  cvt_bf16_k<<<4096, 256, 0, stream>>>(Wih, Wihb, (long)(2LL * 8192 * 2048 / 4));
  cvt_bf16_k<<<4096, 256, 0, stream>>>(Whh, Whhb, (long)(2LL * 8192 * 2048 / 4));
  cvt_bf16_k<<<1024, 256, 0, stream>>>(Wout, Woutb, (long)(2048LL * 2048 / 4));
  init_k<<<256, 256, 0, stream>>>(h0, c0, xbf, h0bf, h1bf, c0f, c1f, bar);
  lstm_persist<<<NWG, NTHR, 0, stream>>>(Wihb, Whhb, Woutb, bih, bhh, bout,
                                         xbf, h0bf, h1bf, c0f, c1f, out, T, bar);
}

// Round 3
// 7602.478 us; speedup vs baseline: 1.7879x; 1.0705x over previous
//
#include <hip/hip_runtime.h>

// ---------------------------------------------------------------------------
// dLSTM: 2-layer LSTM (B=32, H=2048) + projected feedback, seq_len=128.
// R3: (1) weights + activations pre-packed into MFMA-fragment-contiguous
// layout (each 64-lane fragment = 1KB contiguous) so ALL persistent-kernel
// loads are fully-coalesced 8-line bursts — R2's fragment gathers touched 16
// distinct 4KB-strided lines per load and hit a per-CU MLP wall (~19us/phase
// latency-bound, matching measurement). (2) 1024-thr wgs: 16 waves/CU (50%
// occupancy) for 2x memory-level parallelism. Hierarchical relaxed barrier
// from R2 kept.
// ---------------------------------------------------------------------------

typedef __attribute__((ext_vector_type(8))) short short8;
typedef __attribute__((ext_vector_type(4))) short short4v;
typedef __attribute__((ext_vector_type(4))) float f32x4;

#define MFMA16(a, b, c) __builtin_amdgcn_mfma_f32_16x16x32_bf16((a), (b), (c), 0, 0, 0)

static constexpr int BATCH = 32;
static constexpr int HID = 2048;
static constexpr int NWG = 256;
static constexpr int NTHR = 1024;   // 16 waves

__device__ __forceinline__ unsigned short f2bf(float x) {
  unsigned u = __float_as_uint(x);
  u += 0x7FFFu + ((u >> 16) & 1u);   // RNE
  return (unsigned short)(u >> 16);
}

__device__ __forceinline__ float sigm(float x) { return 1.f / (1.f + __expf(-x)); }
__device__ __forceinline__ float tanh_(float x) {
  float e = __expf(2.f * x);
  return 1.f - 2.f / (e + 1.f);
}

// ---------------- weight pack: f32 [8192][2048] -> fragment layout ---------
// dst chunk layout: [layer(2)][wg(256)][tile(2)][kblk(64)][lane(64)][e(8)] bf16
// chunk (wg,tile,kblk) holds B-fragment rows:
//   row = tile*4096 + (nn<8 ? wg*8+nn : 2048+wg*8+nn-8),  nn = lane&15
//   k   = kblk*32 + (lane>>4)*8 + e
__global__ void pack_W_k(const float* __restrict__ src, unsigned short* __restrict__ dst) {
  const int bid = blockIdx.x;              // 1024 blocks: [layer][wg][tile]
  const int layer = bid >> 9, wg = (bid >> 1) & 255, tile = bid & 1;
  const int tid = threadIdx.x;             // 256 threads
  __shared__ __align__(16) unsigned short L[16][2056];

  const float* base = src + ((size_t)layer * 8192) * 2048;
  for (int i = tid; i < 16 * 512; i += 256) {
    const int r = i >> 9, c4 = i & 511;
    const int gr = tile * 4096 + (r < 8 ? wg * 8 + r : 2048 + wg * 8 + r - 8);
    float4 v = ((const float4*)(base + (size_t)gr * 2048))[c4];
    short4v o;
    o.x = (short)f2bf(v.x); o.y = (short)f2bf(v.y);
    o.z = (short)f2bf(v.z); o.w = (short)f2bf(v.w);
    *(short4v*)&L[r][c4 * 4] = o;
  }
  __syncthreads();
  short8* dchunks = (short8*)dst;
  const size_t cbase = ((size_t)layer * 512 + wg * 2 + tile) * 64;  // chunk idx base
  for (int c = tid; c < 4096; c += 256) {
    const int lane = c & 63, kblk = c >> 6;
    const int nn = lane & 15, kb = (lane >> 4) << 3;
    short8 v = *(const short8*)&L[nn][kblk * 32 + kb];
    dchunks[(cbase + kblk) * 64 + lane] = v;
  }
}

// W_out pack: [wg(128)][kblk(64)][lane][e]; row = wg*16 + nn; k as above
__global__ void pack_Wo_k(const float* __restrict__ src, unsigned short* __restrict__ dst) {
  const int wg = blockIdx.x;               // 128 blocks
  const int tid = threadIdx.x;
  __shared__ __align__(16) unsigned short L[16][2056];
  for (int i = tid; i < 16 * 512; i += 256) {
    const int r = i >> 9, c4 = i & 511;
    float4 v = ((const float4*)(src + (size_t)(wg * 16 + r) * 2048))[c4];
    short4v o;
    o.x = (short)f2bf(v.x); o.y = (short)f2bf(v.y);
    o.z = (short)f2bf(v.z); o.w = (short)f2bf(v.w);
    *(short4v*)&L[r][c4 * 4] = o;
  }
  __syncthreads();
  short8* dchunks = (short8*)dst;
  const size_t cbase = (size_t)wg * 64;
  for (int c = tid; c < 4096; c += 256) {
    const int lane = c & 63, kblk = c >> 6;
    const int nn = lane & 15, kb = (lane >> 4) << 3;
    short8 v = *(const short8*)&L[nn][kblk * 32 + kb];
    dchunks[(cbase + kblk) * 64 + lane] = v;
  }
}

// ---------------- per-call state init (packed A layout) --------------------
// A pack layout per matrix: [mtile(2)][kblk(64)][lane(64)][e(8)];
//   m = mtile*16 + (lane&15); k = kblk*32 + (lane>>4)*8 + e
__global__ void init_k(const float* __restrict__ h0, const float* __restrict__ c0,
                       unsigned short* xp, unsigned short* h0p, unsigned short* h1p,
                       float* c0f, float* c1f, unsigned* bar) {
  int i = blockIdx.x * blockDim.x + threadIdx.x;   // 65536 threads
  if (i < BATCH * HID) {
    const int e = i & 7, lane = (i >> 3) & 63, kblk = (i >> 9) & 63, mtile = i >> 15;
    const int m = mtile * 16 + (lane & 15);
    const int k = kblk * 32 + ((lane >> 4) << 3) + e;
    xp[i] = 0;
    h0p[i] = f2bf(h0[m * HID + k]);
    h1p[i] = f2bf(h0[BATCH * HID + m * HID + k]);
    c0f[i] = c0[i];            // c stays in natural [b][col] layout
    c1f[i] = c0[BATCH * HID + i];
  }
  if (i < 320) bar[i] = 0u;
}

// ---------------- hierarchical device-scope grid barrier -------------------
__device__ __forceinline__ void grid_barrier(unsigned* bar, int bno) {
  __syncthreads();
  if (threadIdx.x == 0) {
    __builtin_amdgcn_fence(__ATOMIC_RELEASE, "agent");
    const int g = blockIdx.x >> 5;
    unsigned a = __hip_atomic_fetch_add(&bar[g * 32], 1u,
                                        __ATOMIC_RELAXED, __HIP_MEMORY_SCOPE_AGENT);
    if (a == (unsigned)(32 * bno - 1)) {
      unsigned m = __hip_atomic_fetch_add(&bar[256], 1u,
                                          __ATOMIC_RELAXED, __HIP_MEMORY_SCOPE_AGENT);
      if (m == (unsigned)(8 * bno - 1)) {
        __hip_atomic_store(&bar[288], (unsigned)bno,
                           __ATOMIC_RELAXED, __HIP_MEMORY_SCOPE_AGENT);
      }
    }
    while (__hip_atomic_load(&bar[288], __ATOMIC_RELAXED,
                             __HIP_MEMORY_SCOPE_AGENT) < (unsigned)bno) {
      __builtin_amdgcn_s_sleep(2);
    }
    __builtin_amdgcn_fence(__ATOMIC_ACQUIRE, "agent");
  }
  __syncthreads();
}

// ---------------- one LSTM layer (16 waves, packed operands) ---------------
// wave wv: part = wv>>3 (0: x/W_ih, 1: h/W_hh), kb_base = (wv&7)*8, 8 kblks.
__device__ __forceinline__ void layer_phase(
    int wg, int tid,
    const unsigned short* __restrict__ A1, const unsigned short* __restrict__ A2,
    const unsigned short* __restrict__ W1, const unsigned short* __restrict__ W2,
    const float* __restrict__ bi, const float* __restrict__ bh,
    float* __restrict__ c, unsigned short* __restrict__ houtp,
    float* __restrict__ outp,
    float (*red)[4][64][4]) {
  const int wv = tid >> 6, lane = tid & 63;
  const int part = wv >> 3;
  const int kb_base = (wv & 7) * 8;
  const unsigned short* A = part ? A2 : A1;
  const unsigned short* W = part ? W2 : W1;

  const short8* pA0 = (const short8*)A + (size_t)(0 * 64 + kb_base) * 64 + lane;
  const short8* pA1 = (const short8*)A + (size_t)(1 * 64 + kb_base) * 64 + lane;
  const short8* pB0 = (const short8*)W + ((size_t)(wg * 2 + 0) * 64 + kb_base) * 64 + lane;
  const short8* pB1 = (const short8*)W + ((size_t)(wg * 2 + 1) * 64 + kb_base) * 64 + lane;

  f32x4 acc00 = {0.f, 0.f, 0.f, 0.f}, acc01 = acc00, acc10 = acc00, acc11 = acc00;

  short8 A0s[4], A1s[4], B0s[4], B1s[4];
#pragma unroll
  for (int p = 0; p < 3; ++p) {
    A0s[p] = pA0[64 * p]; A1s[p] = pA1[64 * p];
    B0s[p] = pB0[64 * p]; B1s[p] = pB1[64 * p];
  }
#pragma unroll
  for (int it = 0; it < 8; ++it) {
    const int cs = it & 3;
    const int ps = (it + 3) & 3;
    if (it < 5) {
      A0s[ps] = pA0[64 * (it + 3)]; A1s[ps] = pA1[64 * (it + 3)];
      B0s[ps] = pB0[64 * (it + 3)]; B1s[ps] = pB1[64 * (it + 3)];
    }
    acc00 = MFMA16(A0s[cs], B0s[cs], acc00);
    acc01 = MFMA16(A1s[cs], B0s[cs], acc01);
    acc10 = MFMA16(A0s[cs], B1s[cs], acc10);
    acc11 = MFMA16(A1s[cs], B1s[cs], acc11);
  }

  *(f32x4*)&red[wv][0][lane][0] = acc00;
  *(f32x4*)&red[wv][1][lane][0] = acc01;
  *(f32x4*)&red[wv][2][lane][0] = acc10;
  *(f32x4*)&red[wv][3][lane][0] = acc11;
  __syncthreads();

  if (tid < 256) {
    const int b = tid >> 3, cc = tid & 7;
    const int m = b >> 4, br = b & 15;
    const int reg = br & 3, lbase = (br >> 2) << 4;
    float gi = 0.f, gf = 0.f, gg = 0.f, go = 0.f;
#pragma unroll
    for (int w = 0; w < 16; ++w) {
      gi += red[w][m][lbase + cc][reg];
      gf += red[w][m][lbase + cc + 8][reg];
      gg += red[w][2 + m][lbase + cc][reg];
      go += red[w][2 + m][lbase + cc + 8][reg];
    }
    const int j0 = wg * 8;
    const int col = j0 + cc;
    gi += bi[col] + bh[col];
    gf += bi[2048 + col] + bh[2048 + col];
    gg += bi[4096 + col] + bh[4096 + col];
    go += bi[6144 + col] + bh[6144 + col];
    const float iv = sigm(gi);
    const float fv = sigm(gf);
    const float gv = tanh_(gg);
    const float ov = sigm(go);
    const float cold = c[b * HID + col];
    const float cnew = fv * cold + iv * gv;
    const float hnew = ov * tanh_(cnew);
    c[b * HID + col] = cnew;
    // packed A-layout write of h_new
    const int kblk = col >> 5, lh = (col >> 3) & 3, e = col & 7;
    const int lane_p = (b & 15) | (lh << 4), mtile = b >> 4;
    houtp[((size_t)(mtile * 64 + kblk) * 64 + lane_p) * 8 + e] = f2bf(hnew);
    if (outp) outp[b * HID + col] = hnew;
  }
}

// ---------------- projection (packed), 128 active wgs ----------------------
__device__ __forceinline__ void proj_phase(
    int wg, int tid,
    const unsigned short* __restrict__ Ap,
    const unsigned short* __restrict__ Wo,
    const float* __restrict__ bout,
    unsigned short* __restrict__ xp,
    float (*red)[4][64][4]) {
  const int wv = tid >> 6, lane = tid & 63;
  const int kb_base = wv * 4;       // 16 waves x 4 kblk = 64
  const int m0 = wg * 16;

  const short8* pA0 = (const short8*)Ap + (size_t)(0 * 64 + kb_base) * 64 + lane;
  const short8* pA1 = (const short8*)Ap + (size_t)(1 * 64 + kb_base) * 64 + lane;
  const short8* pB = (const short8*)Wo + ((size_t)wg * 64 + kb_base) * 64 + lane;

  short8 a0[4], a1[4], bb[4];
#pragma unroll
  for (int it = 0; it < 4; ++it) {
    a0[it] = pA0[64 * it]; a1[it] = pA1[64 * it]; bb[it] = pB[64 * it];
  }
  f32x4 acc0 = {0.f, 0.f, 0.f, 0.f}, acc1 = acc0;
#pragma unroll
  for (int it = 0; it < 4; ++it) {
    acc0 = MFMA16(a0[it], bb[it], acc0);
    acc1 = MFMA16(a1[it], bb[it], acc1);
  }
  *(f32x4*)&red[wv][0][lane][0] = acc0;
  *(f32x4*)&red[wv][1][lane][0] = acc1;
  __syncthreads();

  if (tid < 512) {
    const int b = tid >> 4, cc = tid & 15;
    const int m = b >> 4, br = b & 15;
    const int reg = br & 3, lane_r = ((br >> 2) << 4) | cc;
    float x = 0.f;
#pragma unroll
    for (int w = 0; w < 16; ++w) x += red[w][m][lane_r][reg];
    const int xcol = m0 + cc;
    x += bout[xcol];
    const int kblk = xcol >> 5, lh = (xcol >> 3) & 3, e = xcol & 7;
    const int lane_p = (b & 15) | (lh << 4), mtile = b >> 4;
    xp[((size_t)(mtile * 64 + kblk) * 64 + lane_p) * 8 + e] = f2bf(x);
  }
}

// ---------------- persistent driver ----------------------------------------
__global__ __launch_bounds__(NTHR, 1) void lstm_persist(
    const unsigned short* __restrict__ Wihb,   // packed [2][256][2][64][512]
    const unsigned short* __restrict__ Whhb,   // packed
    const unsigned short* __restrict__ Woutb,  // packed [128][64][512]
    const float* __restrict__ bih, const float* __restrict__ bhh,
    const float* __restrict__ bout,
    unsigned short* xp,
    unsigned short* h0p,    // [2] ping-pong, packed
    unsigned short* h1p,    // [2] ping-pong, packed
    float* c0f, float* c1f,
    float* __restrict__ out, int T, unsigned* bar) {
  __shared__ float red[16][4][64][4];   // 64 KiB
  const int wg = blockIdx.x, tid = threadIdx.x;
  const size_t BH = (size_t)BATCH * HID;
  const size_t WL = (size_t)8192 * 2048;   // elems per layer in packed W arrays
  int bno = 1;

  for (int t = 0; t < T; ++t) {
    const int par = t & 1;
    layer_phase(wg, tid, xp, h0p + par * BH,
                Wihb, Whhb, bih, bhh,
                c0f, h0p + (par ^ 1) * BH, (float*)nullptr, red);
    grid_barrier(bar, bno++);
    layer_phase(wg, tid, h0p + (par ^ 1) * BH, h1p + par * BH,
                Wihb + WL, Whhb + WL, bih + 8192, bhh + 8192,
                c1f, h1p + (par ^ 1) * BH, out + (size_t)t * BH, red);
    grid_barrier(bar, bno++);
    if (wg < 128) proj_phase(wg, tid, h1p + (par ^ 1) * BH, Woutb, bout, xp, red);
    grid_barrier(bar, bno++);
  }
}

// ---------------------------------------------------------------------------
extern "C" void kernel_launch(void* const* d_in, const int* in_sizes, int n_in,
                              void* d_out, int out_size, void* d_ws, size_t ws_size,
                              hipStream_t stream) {
  const float* h0 = (const float*)d_in[0];
  const float* c0 = (const float*)d_in[1];
  const float* Wih = (const float*)d_in[2];
  const float* Whh = (const float*)d_in[3];
  const float* bih = (const float*)d_in[4];
  const float* bhh = (const float*)d_in[5];
  const float* Wout = (const float*)d_in[6];
  const float* bout = (const float*)d_in[7];
  float* out = (float*)d_out;
  const int T = out_size / (BATCH * HID);

  unsigned short* Wihb = (unsigned short*)d_ws;             // 33,554,432 elems
  unsigned short* Whhb = Wihb + (size_t)33554432;           // 33,554,432
  unsigned short* Woutb = Whhb + (size_t)33554432;          // 4,194,304
  unsigned short* xp = Woutb + (size_t)4194304;             // 65,536
  unsigned short* h0p = xp + 65536;                         // 131,072 (x2)
  unsigned short* h1p = h0p + 131072;                       // 131,072
  float* c0f = (float*)(h1p + 131072);                      // 65,536 f32
  float* c1f = c0f + 65536;                                 // 65,536 f32
  unsigned* bar = (unsigned*)(c1f + 65536);                 // 320 u32

  pack_W_k<<<1024, 256, 0, stream>>>(Wih, Wihb);
  pack_W_k<<<1024, 256, 0, stream>>>(Whh, Whhb);
  pack_Wo_k<<<128, 256, 0, stream>>>(Wout, Woutb);
  init_k<<<256, 256, 0, stream>>>(h0, c0, xp, h0p, h1p, c0f, c1f, bar);
  lstm_persist<<<NWG, NTHR, 0, stream>>>(Wihb, Whhb, Woutb, bih, bhh, bout,
                                         xp, h0p, h1p, c0f, c1f, out, T, bar);
}

// Round 4
// 3724.693 us; speedup vs baseline: 3.6493x; 2.0411x over previous
//
#include <hip/hip_runtime.h>

// ---------------------------------------------------------------------------
// dLSTM R4: PERSISTENT WEIGHTS. R3 showed streaming 142MB/step of weights is
// MSHR-latency-walled at ~19.5us/phase (~64 lines in flight x ~700cy L3 lat
// = ~11 B/cy/CU, matching measurement exactly). Fix: weights live on-chip for
// all 128 steps: per-CU 512KB = 188 VGPRs/thread (376KB, 8 waves) + 136KB
// LDS. Projection folded into layer0 via Wfused = Wih0 @ Wout (precomputed
// on-device, bf16 MFMA GEMM) -> 2 phases + 2 barriers/step, x/W_out gone.
// t=0 uses a zero h1-buffer + unfused bias (x0 = 0, not b_out-fed).
// ---------------------------------------------------------------------------

typedef __attribute__((ext_vector_type(8))) short short8;
typedef __attribute__((ext_vector_type(4))) short short4v;
typedef __attribute__((ext_vector_type(4))) float f32x4;

#define MFMA16(a, b, c) __builtin_amdgcn_mfma_f32_16x16x32_bf16((a), (b), (c), 0, 0, 0)

static constexpr int BATCH = 32;
static constexpr int HID = 2048;
static constexpr int NWG = 256;
static constexpr int NTHR = 512;           // 8 waves
static constexpr int BH = BATCH * HID;     // 65536
static constexpr size_t WMAT = (size_t)8192 * 2048;
static constexpr int LDS_RED_OFF = 139264; // 8 waves * 17 chunks * 1KB
static constexpr int LDS_BYTES = 155648;   // + 16KB reduction

__device__ __forceinline__ unsigned short f2bf(float x) {
  unsigned u = __float_as_uint(x);
  u += 0x7FFFu + ((u >> 16) & 1u);
  return (unsigned short)(u >> 16);
}
__device__ __forceinline__ float sigm(float x) { return 1.f / (1.f + __expf(-x)); }
__device__ __forceinline__ float tanh_(float x) {
  float e = __expf(2.f * x);
  return 1.f - 2.f / (e + 1.f);
}

__global__ void cvt_bf16_k(const float* __restrict__ s, unsigned short* __restrict__ d,
                           long n4) {
  long i = blockIdx.x * (long)blockDim.x + threadIdx.x;
  long st = (long)gridDim.x * blockDim.x;
  for (; i < n4; i += st) {
    float4 v = ((const float4*)s)[i];
    short4v o;
    o.x = (short)f2bf(v.x); o.y = (short)f2bf(v.y);
    o.z = (short)f2bf(v.z); o.w = (short)f2bf(v.w);
    ((short4v*)d)[i] = o;
  }
}

// Wout f32 [2048][2048] -> WoutT bf16 transposed
__global__ void tcvt_k(const float* __restrict__ src, unsigned short* __restrict__ dst) {
  __shared__ float T[64][65];
  const int jb = blockIdx.x * 64, kb = blockIdx.y * 64;
  const int tid = threadIdx.x;
#pragma unroll
  for (int r = 0; r < 4; ++r) {
    const int row = r * 16 + (tid >> 4), c4 = (tid & 15) * 4;
    float4 v = *(const float4*)&src[(size_t)(jb + row) * 2048 + kb + c4];
    T[row][c4] = v.x; T[row][c4 + 1] = v.y; T[row][c4 + 2] = v.z; T[row][c4 + 3] = v.w;
  }
  __syncthreads();
#pragma unroll
  for (int r = 0; r < 4; ++r) {
    const int k = r * 16 + (tid >> 4), j4 = (tid & 15) * 4;
    short4v o;
    o.x = (short)f2bf(T[j4][k]);     o.y = (short)f2bf(T[j4 + 1][k]);
    o.z = (short)f2bf(T[j4 + 2][k]); o.w = (short)f2bf(T[j4 + 3][k]);
    *(short4v*)&dst[(size_t)(kb + k) * 2048 + jb + j4] = o;
  }
}

// Wfp(packed) = A[8192x2048] . Bt[2048x2048]^T ; grid(64,16), 4 waves (2x2)
__global__ void gemm_pack_k(const unsigned short* __restrict__ A,
                            const unsigned short* __restrict__ Bt,
                            unsigned short* __restrict__ Wfp) {
  __shared__ __align__(16) unsigned short As[128][72], Bs[128][72];
  const int tid = threadIdx.x, wv = tid >> 6, lane = tid & 63;
  const int wm = wv >> 1, wn = wv & 1;
  const int g0 = blockIdx.x * 128, k0 = blockIdx.y * 128;
  f32x4 acc[4][4];
#pragma unroll
  for (int i = 0; i < 4; ++i)
#pragma unroll
    for (int j = 0; j < 4; ++j) acc[i][j] = (f32x4){0.f, 0.f, 0.f, 0.f};

  for (int kt = 0; kt < 32; ++kt) {
#pragma unroll
    for (int rr = 0; rr < 4; ++rr) {
      const int row = rr * 32 + (tid >> 3), c8 = (tid & 7) * 8;
      *(short8*)&As[row][c8] = *(const short8*)&A[(size_t)(g0 + row) * 2048 + kt * 64 + c8];
      *(short8*)&Bs[row][c8] = *(const short8*)&Bt[(size_t)(k0 + row) * 2048 + kt * 64 + c8];
    }
    __syncthreads();
#pragma unroll
    for (int kk = 0; kk < 2; ++kk) {
      short8 af[4], bf[4];
#pragma unroll
      for (int mi = 0; mi < 4; ++mi)
        af[mi] = *(const short8*)&As[wm * 64 + mi * 16 + (lane & 15)][kk * 32 + (lane >> 4) * 8];
#pragma unroll
      for (int ni = 0; ni < 4; ++ni)
        bf[ni] = *(const short8*)&Bs[wn * 64 + ni * 16 + (lane & 15)][kk * 32 + (lane >> 4) * 8];
#pragma unroll
      for (int mi = 0; mi < 4; ++mi)
#pragma unroll
        for (int ni = 0; ni < 4; ++ni)
          acc[mi][ni] = MFMA16(af[mi], bf[ni], acc[mi][ni]);
    }
    __syncthreads();
  }
#pragma unroll
  for (int mi = 0; mi < 4; ++mi)
#pragma unroll
    for (int ni = 0; ni < 4; ++ni)
#pragma unroll
      for (int r = 0; r < 4; ++r) {
        const int g = g0 + wm * 64 + mi * 16 + (lane >> 4) * 4 + r;
        const int k = k0 + wn * 64 + ni * 16 + (lane & 15);
        const int gateblk = g >> 11, gcol = g & 2047;
        const int wgp = gcol >> 3, nn = (gcol & 7) + 8 * (gateblk & 1), tile = gateblk >> 1;
        const int kblk = k >> 5, e = k & 7, lane_p = nn + 16 * ((k >> 3) & 3);
        Wfp[(((size_t)(wgp * 2 + tile) * 64 + kblk) * 64 + lane_p) * 8 + e] =
            f2bf(acc[mi][ni][r]);
      }
}

__global__ void pack_W1_k(const float* __restrict__ src, unsigned short* __restrict__ dst) {
  const int bid = blockIdx.x;              // 512: [wg(256)][tile(2)]
  const int wg = bid >> 1, tile = bid & 1;
  const int tid = threadIdx.x;
  __shared__ __align__(16) unsigned short L[16][2056];
  for (int i = tid; i < 16 * 512; i += 256) {
    const int r = i >> 9, c4 = i & 511;
    const int gr = tile * 4096 + (r < 8 ? wg * 8 + r : 2048 + wg * 8 + r - 8);
    float4 v = ((const float4*)(src + (size_t)gr * 2048))[c4];
    short4v o;
    o.x = (short)f2bf(v.x); o.y = (short)f2bf(v.y);
    o.z = (short)f2bf(v.z); o.w = (short)f2bf(v.w);
    *(short4v*)&L[r][c4 * 4] = o;
  }
  __syncthreads();
  short8* dchunks = (short8*)dst;
  const size_t cbase = (size_t)(wg * 2 + tile) * 64;
  for (int c = tid; c < 4096; c += 256) {
    const int lane = c & 63, kblk = c >> 6;
    const int nn = lane & 15, kb = (lane >> 4) << 3;
    short8 v = *(const short8*)&L[nn][kblk * 32 + kb];
    dchunks[(cbase + kblk) * 64 + lane] = v;
  }
}

__global__ void bias_k(const float* __restrict__ Wih, const float* __restrict__ bout,
                       const float* __restrict__ bih, const float* __restrict__ bhh,
                       float* bA0, float* bAf, float* bB) {
  const int g = blockIdx.x * 8 + (threadIdx.x >> 6);
  const int lane = threadIdx.x & 63;
  float s = 0.f;
  for (int i = 0; i < 32; ++i)
    s += Wih[(size_t)g * 2048 + i * 64 + lane] * bout[i * 64 + lane];
  for (int off = 32; off; off >>= 1) s += __shfl_down(s, off);
  if (lane == 0) {
    const float b0 = bih[g] + bhh[g];
    bA0[g] = b0; bAf[g] = b0 + s;
    bB[g] = bih[8192 + g] + bhh[8192 + g];
  }
}

__global__ void init_k(const float* __restrict__ h0, const float* __restrict__ c0,
                       unsigned short* h0p, unsigned short* h1p, unsigned short* zbuf,
                       float* c0f, float* c1f, unsigned* bar) {
  int i = blockIdx.x * blockDim.x + threadIdx.x;
  if (i < BH) {
    const int e = i & 7, lane = (i >> 3) & 63, kblk = (i >> 9) & 63, mtile = i >> 15;
    const int m = mtile * 16 + (lane & 15);
    const int k = kblk * 32 + ((lane >> 4) << 3) + e;
    h0p[i] = f2bf(h0[m * HID + k]);
    h1p[i] = f2bf(h0[BH + m * HID + k]);
    zbuf[i] = 0;
    c0f[i] = c0[i];
    c1f[i] = c0[BH + i];
  }
  if (i < 320) bar[i] = 0u;
}

__device__ __forceinline__ void grid_barrier(unsigned* bar, int bno) {
  __syncthreads();
  if (threadIdx.x == 0) {
    __builtin_amdgcn_fence(__ATOMIC_RELEASE, "agent");
    const int g = blockIdx.x >> 5;
    unsigned a = __hip_atomic_fetch_add(&bar[g * 32], 1u,
                                        __ATOMIC_RELAXED, __HIP_MEMORY_SCOPE_AGENT);
    if (a == (unsigned)(32 * bno - 1)) {
      unsigned m = __hip_atomic_fetch_add(&bar[256], 1u,
                                          __ATOMIC_RELAXED, __HIP_MEMORY_SCOPE_AGENT);
      if (m == (unsigned)(8 * bno - 1)) {
        __hip_atomic_store(&bar[288], (unsigned)bno,
                           __ATOMIC_RELAXED, __HIP_MEMORY_SCOPE_AGENT);
      }
    }
    while (__hip_atomic_load(&bar[288], __ATOMIC_RELAXED,
                             __HIP_MEMORY_SCOPE_AGENT) < (unsigned)bno) {
      __builtin_amdgcn_s_sleep(2);
    }
    __builtin_amdgcn_fence(__ATOMIC_ACQUIRE, "agent");
  }
  __syncthreads();
}

#define PHASE_BODY(VARR, NV2, LBASE, CBUF, HOUTP, OUTP, BSEL)                     \
  {                                                                               \
    const short8* pa0 = (const short8*)Asrc + (size_t)(ks * 16) * 64 + lane;      \
    const short8* pa1 = pa0 + (size_t)64 * 64;                                    \
    f32x4 acc00 = {0.f, 0.f, 0.f, 0.f}, acc01 = acc00, acc10 = acc00, acc11 = acc00; \
    _Pragma("unroll")                                                             \
    for (int kk = 0; kk < NV2; ++kk) {                                            \
      short8 a0 = pa0[kk * 64], a1 = pa1[kk * 64];                                \
      short8 b0 = VARR[kk], b1 = VARR[16 + kk];                                   \
      acc00 = MFMA16(a0, b0, acc00); acc01 = MFMA16(a1, b0, acc01);               \
      acc10 = MFMA16(a0, b1, acc10); acc11 = MFMA16(a1, b1, acc11);               \
    }                                                                             \
    _Pragma("unroll")                                                             \
    for (int kk = NV2; kk < 16; ++kk) {                                           \
      short8 a0 = pa0[kk * 64], a1 = pa1[kk * 64];                                \
      short8 b0 = VARR[kk];                                                       \
      short8 b1 = lw[(w * 17 + LBASE + (kk - NV2)) * 64 + lane];                  \
      acc00 = MFMA16(a0, b0, acc00); acc01 = MFMA16(a1, b0, acc01);               \
      acc10 = MFMA16(a0, b1, acc10); acc11 = MFMA16(a1, b1, acc11);               \
    }                                                                             \
    *(f32x4*)&red[((w * 2 + 0) * 64 + lane) * 4] = acc00;                         \
    *(f32x4*)&red[((w * 2 + 1) * 64 + lane) * 4] = acc01;                         \
    __syncthreads();                                                              \
    float gi = 0.f, gf_ = 0.f;                                                    \
    if (tid < 256) {                                                              \
      const int b = tid >> 3, cc = tid & 7, m = b >> 4, br = b & 15;              \
      const int reg = br & 3, lb = (br >> 2) << 4;                                \
      _Pragma("unroll")                                                           \
      for (int ww = 0; ww < 8; ++ww) {                                            \
        gi  += red[((ww * 2 + m) * 64 + lb + cc) * 4 + reg];                      \
        gf_ += red[((ww * 2 + m) * 64 + lb + cc + 8) * 4 + reg];                  \
      }                                                                           \
    }                                                                             \
    __syncthreads();                                                              \
    *(f32x4*)&red[((w * 2 + 0) * 64 + lane) * 4] = acc10;                         \
    *(f32x4*)&red[((w * 2 + 1) * 64 + lane) * 4] = acc11;                         \
    __syncthreads();                                                              \
    if (tid < 256) {                                                              \
      const int b = tid >> 3, cc = tid & 7, m = b >> 4, br = b & 15;              \
      const int reg = br & 3, lb = (br >> 2) << 4;                                \
      float gg = 0.f, go = 0.f;                                                   \
      _Pragma("unroll")                                                           \
      for (int ww = 0; ww < 8; ++ww) {                                            \
        gg += red[((ww * 2 + m) * 64 + lb + cc) * 4 + reg];                       \
        go += red[((ww * 2 + m) * 64 + lb + cc + 8) * 4 + reg];                   \
      }                                                                           \
      const int col = wg * 8 + cc;                                                \
      gi  += (BSEL)[col];                                                         \
      gf_ += (BSEL)[2048 + col];                                                  \
      gg  += (BSEL)[4096 + col];                                                  \
      go  += (BSEL)[6144 + col];                                                  \
      const float iv = sigm(gi), fv = sigm(gf_), gv = tanh_(gg), ov = sigm(go);   \
      const float cold = (CBUF)[b * HID + col];                                   \
      const float cnew = fv * cold + iv * gv;                                     \
      const float hnew = ov * tanh_(cnew);                                        \
      (CBUF)[b * HID + col] = cnew;                                               \
      const int kblk = col >> 5, lh = (col >> 3) & 3, e = col & 7;                \
      const int lane_p = (b & 15) | (lh << 4), mt = b >> 4;                       \
      (HOUTP)[((size_t)(mt * 64 + kblk) * 64 + lane_p) * 8 + e] = f2bf(hnew);     \
      if (OUTP) ((float*)(OUTP))[b * HID + col] = hnew;                           \
    }                                                                             \
  }

__global__ __launch_bounds__(NTHR, 1) void lstm_persist(
    const unsigned short* __restrict__ Wfp, const unsigned short* __restrict__ Wh0p,
    const unsigned short* __restrict__ Wi1p, const unsigned short* __restrict__ Wh1p,
    const float* __restrict__ bA0, const float* __restrict__ bAf,
    const float* __restrict__ bB,
    unsigned short* h0p, unsigned short* h1p, const unsigned short* zbuf,
    float* c0f, float* c1f, float* __restrict__ out, int T, unsigned* bar) {
  extern __shared__ __align__(16) char smem[];
  short8* lw = (short8*)smem;
  float* red = (float*)(smem + LDS_RED_OFF);
  const int wg = blockIdx.x, tid = threadIdx.x;
  const int w = tid >> 6, lane = tid & 63, ks = w & 3;
  const unsigned short* M0 = (w < 4) ? Wfp : Wh0p;
  const unsigned short* M1 = (w < 4) ? Wi1p : Wh1p;

  short8 v0[24], v1[23];
  {
    const short8* m0c = (const short8*)M0;
    const short8* m1c = (const short8*)M1;
#pragma unroll
    for (int c = 0; c < 24; ++c)
      v0[c] = m0c[(((size_t)(wg * 2 + (c >> 4)) * 64) + ks * 16 + (c & 15)) * 64 + lane];
#pragma unroll
    for (int c = 24; c < 32; ++c)
      lw[(w * 17 + (c - 24)) * 64 + lane] =
          m0c[(((size_t)(wg * 2 + (c >> 4)) * 64) + ks * 16 + (c & 15)) * 64 + lane];
#pragma unroll
    for (int c = 0; c < 23; ++c)
      v1[c] = m1c[(((size_t)(wg * 2 + (c >> 4)) * 64) + ks * 16 + (c & 15)) * 64 + lane];
#pragma unroll
    for (int c = 23; c < 32; ++c)
      lw[(w * 17 + 8 + (c - 23)) * 64 + lane] =
          m1c[(((size_t)(wg * 2 + (c >> 4)) * 64) + ks * 16 + (c & 15)) * 64 + lane];
  }
  __syncthreads();

  int bno = 1;
  for (int t = 0; t < T; ++t) {
    const int par = t & 1;
    {  // phase A
      const unsigned short* Asrc =
          (w < 4) ? ((t == 0) ? zbuf : h1p + par * BH) : (h0p + par * BH);
      const float* bsel = (t == 0) ? bA0 : bAf;
      PHASE_BODY(v0, 8, 0, c0f, h0p + (par ^ 1) * BH, (float*)nullptr, bsel)
    }
    grid_barrier(bar, bno++);
    {  // phase B
      const unsigned short* Asrc = (w < 4) ? (h0p + (par ^ 1) * BH) : (h1p + par * BH);
      PHASE_BODY(v1, 7, 8, c1f, h1p + (par ^ 1) * BH, out + (size_t)t * BH, bB)
    }
    grid_barrier(bar, bno++);
  }
}

extern "C" void kernel_launch(void* const* d_in, const int* in_sizes, int n_in,
                              void* d_out, int out_size, void* d_ws, size_t ws_size,
                              hipStream_t stream) {
  const float* h0 = (const float*)d_in[0];
  const float* c0 = (const float*)d_in[1];
  const float* Wih = (const float*)d_in[2];
  const float* Whh = (const float*)d_in[3];
  const float* bih = (const float*)d_in[4];
  const float* bhh = (const float*)d_in[5];
  const float* Wout = (const float*)d_in[6];
  const float* bout = (const float*)d_in[7];
  float* out = (float*)d_out;
  const int T = out_size / BH;

  unsigned short* Wfp = (unsigned short*)d_ws;
  unsigned short* Wh0p = Wfp + WMAT;
  unsigned short* Wi1p = Wfp + 2 * WMAT;
  unsigned short* Wh1p = Wfp + 3 * WMAT;
  unsigned short* tmpA = Wi1p;    // alias, dead after gemm_pack_k
  unsigned short* WoutT = Wh1p;   // alias, dead after gemm_pack_k
  unsigned short* S = Wfp + 4 * WMAT;
  unsigned short* h0p = S;
  unsigned short* h1p = S + 131072;
  unsigned short* zbuf = S + 262144;
  float* F = (float*)(S + 327680);
  float* c0f = F;
  float* c1f = F + 65536;
  float* bA0 = F + 131072;
  float* bAf = F + 139264;
  float* bB = F + 147456;
  unsigned* bar = (unsigned*)(F + 155648);

  cvt_bf16_k<<<2048, 256, 0, stream>>>(Wih, tmpA, (long)(WMAT / 4));
  tcvt_k<<<dim3(32, 32), 256, 0, stream>>>(Wout, WoutT);
  gemm_pack_k<<<dim3(64, 16), 256, 0, stream>>>(tmpA, WoutT, Wfp);
  pack_W1_k<<<512, 256, 0, stream>>>(Whh, Wh0p);
  pack_W1_k<<<512, 256, 0, stream>>>(Wih + WMAT, Wi1p);
  pack_W1_k<<<512, 256, 0, stream>>>(Whh + WMAT, Wh1p);
  bias_k<<<1024, 512, 0, stream>>>(Wih, bout, bih, bhh, bA0, bAf, bB);
  init_k<<<256, 256, 0, stream>>>(h0, c0, h0p, h1p, zbuf, c0f, c1f, bar);

  (void)hipFuncSetAttribute((const void*)lstm_persist,
                            hipFuncAttributeMaxDynamicSharedMemorySize, LDS_BYTES);
  lstm_persist<<<NWG, NTHR, LDS_BYTES, stream>>>(Wfp, Wh0p, Wi1p, Wh1p,
                                                 bA0, bAf, bB,
                                                 h0p, h1p, zbuf, c0f, c1f, out, T, bar);
}

// Round 5
// 3681.738 us; speedup vs baseline: 3.6919x; 1.0117x over previous
//
#include <hip/hip_runtime.h>

// ---------------------------------------------------------------------------
// dLSTM R5: fence-free phase exchange. R4's 13.8us/phase = agent-fence L2
// invalidate + A-loads MSHR-walled from L3 (256KB/CU @ ~11.7 B/cy = 9.2us).
// New scheme per phase:
//   producers store h via sc0sc1 (device-coherent) stores to hG (L3-visible),
//   counter-only global barrier (no cache fences),
//   16 copier wgs per *physical* XCD (s_getreg XCC_ID + atomic election)
//     copy hG -> X[xcd] with sc0sc1 loads + NORMAL stores (dirty in own L2),
//   XCD-local counter barrier, L1-only buffer_inv,
//   compute reads A-fragments from X[xcd] = local-L2 hits at full L2 BW.
// Weights stay register/LDS-resident (R4). c/out/biases normal cached.
// ---------------------------------------------------------------------------

typedef __attribute__((ext_vector_type(8))) short short8;
typedef __attribute__((ext_vector_type(4))) short short4v;
typedef __attribute__((ext_vector_type(4))) float f32x4;
typedef __attribute__((ext_vector_type(4))) unsigned int u32x4;

#define MFMA16(a, b, c) __builtin_amdgcn_mfma_f32_16x16x32_bf16((a), (b), (c), 0, 0, 0)

static constexpr int BATCH = 32;
static constexpr int HID = 2048;
static constexpr int NWG = 256;
static constexpr int NTHR = 512;           // 8 waves
static constexpr int BH = BATCH * HID;     // 65536
static constexpr size_t WMAT = (size_t)8192 * 2048;
static constexpr int LDS_RED_OFF = 139264; // 8 waves * 17 chunks * 1KB
static constexpr int LDS_BYTES = 155648;   // + 16KB reduction

#define AT_ADD(p, v) __hip_atomic_fetch_add((p), (v), __ATOMIC_RELAXED, __HIP_MEMORY_SCOPE_AGENT)
#define AT_LD(p) __hip_atomic_load((p), __ATOMIC_RELAXED, __HIP_MEMORY_SCOPE_AGENT)
#define AT_ST(p, v) __hip_atomic_store((p), (v), __ATOMIC_RELAXED, __HIP_MEMORY_SCOPE_AGENT)

__device__ __forceinline__ unsigned short f2bf(float x) {
  unsigned u = __float_as_uint(x);
  u += 0x7FFFu + ((u >> 16) & 1u);
  return (unsigned short)(u >> 16);
}
__device__ __forceinline__ float sigm(float x) { return 1.f / (1.f + __expf(-x)); }
__device__ __forceinline__ float tanh_(float x) {
  float e = __expf(2.f * x);
  return 1.f - 2.f / (e + 1.f);
}

__global__ void cvt_bf16_k(const float* __restrict__ s, unsigned short* __restrict__ d,
                           long n4) {
  long i = blockIdx.x * (long)blockDim.x + threadIdx.x;
  long st = (long)gridDim.x * blockDim.x;
  for (; i < n4; i += st) {
    float4 v = ((const float4*)s)[i];
    short4v o;
    o.x = (short)f2bf(v.x); o.y = (short)f2bf(v.y);
    o.z = (short)f2bf(v.z); o.w = (short)f2bf(v.w);
    ((short4v*)d)[i] = o;
  }
}

// Wout f32 [2048][2048] -> WoutT bf16 transposed
__global__ void tcvt_k(const float* __restrict__ src, unsigned short* __restrict__ dst) {
  __shared__ float T[64][65];
  const int jb = blockIdx.x * 64, kb = blockIdx.y * 64;
  const int tid = threadIdx.x;
#pragma unroll
  for (int r = 0; r < 4; ++r) {
    const int row = r * 16 + (tid >> 4), c4 = (tid & 15) * 4;
    float4 v = *(const float4*)&src[(size_t)(jb + row) * 2048 + kb + c4];
    T[row][c4] = v.x; T[row][c4 + 1] = v.y; T[row][c4 + 2] = v.z; T[row][c4 + 3] = v.w;
  }
  __syncthreads();
#pragma unroll
  for (int r = 0; r < 4; ++r) {
    const int k = r * 16 + (tid >> 4), j4 = (tid & 15) * 4;
    short4v o;
    o.x = (short)f2bf(T[j4][k]);     o.y = (short)f2bf(T[j4 + 1][k]);
    o.z = (short)f2bf(T[j4 + 2][k]); o.w = (short)f2bf(T[j4 + 3][k]);
    *(short4v*)&dst[(size_t)(kb + k) * 2048 + jb + j4] = o;
  }
}

// Wfp(packed) = A[8192x2048] . Bt[2048x2048]^T ; grid(64,16), 4 waves (2x2)
__global__ void gemm_pack_k(const unsigned short* __restrict__ A,
                            const unsigned short* __restrict__ Bt,
                            unsigned short* __restrict__ Wfp) {
  __shared__ __align__(16) unsigned short As[128][72], Bs[128][72];
  const int tid = threadIdx.x, wv = tid >> 6, lane = tid & 63;
  const int wm = wv >> 1, wn = wv & 1;
  const int g0 = blockIdx.x * 128, k0 = blockIdx.y * 128;
  f32x4 acc[4][4];
#pragma unroll
  for (int i = 0; i < 4; ++i)
#pragma unroll
    for (int j = 0; j < 4; ++j) acc[i][j] = (f32x4){0.f, 0.f, 0.f, 0.f};

  for (int kt = 0; kt < 32; ++kt) {
#pragma unroll
    for (int rr = 0; rr < 4; ++rr) {
      const int row = rr * 32 + (tid >> 3), c8 = (tid & 7) * 8;
      *(short8*)&As[row][c8] = *(const short8*)&A[(size_t)(g0 + row) * 2048 + kt * 64 + c8];
      *(short8*)&Bs[row][c8] = *(const short8*)&Bt[(size_t)(k0 + row) * 2048 + kt * 64 + c8];
    }
    __syncthreads();
#pragma unroll
    for (int kk = 0; kk < 2; ++kk) {
      short8 af[4], bf[4];
#pragma unroll
      for (int mi = 0; mi < 4; ++mi)
        af[mi] = *(const short8*)&As[wm * 64 + mi * 16 + (lane & 15)][kk * 32 + (lane >> 4) * 8];
#pragma unroll
      for (int ni = 0; ni < 4; ++ni)
        bf[ni] = *(const short8*)&Bs[wn * 64 + ni * 16 + (lane & 15)][kk * 32 + (lane >> 4) * 8];
#pragma unroll
      for (int mi = 0; mi < 4; ++mi)
#pragma unroll
        for (int ni = 0; ni < 4; ++ni)
          acc[mi][ni] = MFMA16(af[mi], bf[ni], acc[mi][ni]);
    }
    __syncthreads();
  }
#pragma unroll
  for (int mi = 0; mi < 4; ++mi)
#pragma unroll
    for (int ni = 0; ni < 4; ++ni)
#pragma unroll
      for (int r = 0; r < 4; ++r) {
        const int g = g0 + wm * 64 + mi * 16 + (lane >> 4) * 4 + r;
        const int k = k0 + wn * 64 + ni * 16 + (lane & 15);
        const int gateblk = g >> 11, gcol = g & 2047;
        const int wgp = gcol >> 3, nn = (gcol & 7) + 8 * (gateblk & 1), tile = gateblk >> 1;
        const int kblk = k >> 5, e = k & 7, lane_p = nn + 16 * ((k >> 3) & 3);
        Wfp[(((size_t)(wgp * 2 + tile) * 64 + kblk) * 64 + lane_p) * 8 + e] =
            f2bf(acc[mi][ni][r]);
      }
}

__global__ void pack_W1_k(const float* __restrict__ src, unsigned short* __restrict__ dst) {
  const int bid = blockIdx.x;              // 512: [wg(256)][tile(2)]
  const int wg = bid >> 1, tile = bid & 1;
  const int tid = threadIdx.x;
  __shared__ __align__(16) unsigned short L[16][2056];
  for (int i = tid; i < 16 * 512; i += 256) {
    const int r = i >> 9, c4 = i & 511;
    const int gr = tile * 4096 + (r < 8 ? wg * 8 + r : 2048 + wg * 8 + r - 8);
    float4 v = ((const float4*)(src + (size_t)gr * 2048))[c4];
    short4v o;
    o.x = (short)f2bf(v.x); o.y = (short)f2bf(v.y);
    o.z = (short)f2bf(v.z); o.w = (short)f2bf(v.w);
    *(short4v*)&L[r][c4 * 4] = o;
  }
  __syncthreads();
  short8* dchunks = (short8*)dst;
  const size_t cbase = (size_t)(wg * 2 + tile) * 64;
  for (int c = tid; c < 4096; c += 256) {
    const int lane = c & 63, kblk = c >> 6;
    const int nn = lane & 15, kb = (lane >> 4) << 3;
    short8 v = *(const short8*)&L[nn][kblk * 32 + kb];
    dchunks[(cbase + kblk) * 64 + lane] = v;
  }
}

__global__ void bias_k(const float* __restrict__ Wih, const float* __restrict__ bout,
                       const float* __restrict__ bih, const float* __restrict__ bhh,
                       float* bA0, float* bAf, float* bB) {
  const int g = blockIdx.x * 8 + (threadIdx.x >> 6);
  const int lane = threadIdx.x & 63;
  float s = 0.f;
  for (int i = 0; i < 32; ++i)
    s += Wih[(size_t)g * 2048 + i * 64 + lane] * bout[i * 64 + lane];
  for (int off = 32; off; off >>= 1) s += __shfl_down(s, off);
  if (lane == 0) {
    const float b0 = bih[g] + bhh[g];
    bA0[g] = b0; bAf[g] = b0 + s;
    bB[g] = bih[8192 + g] + bhh[8192 + g];
  }
}

// init: X[8 xcds][2 matrices] = initial h ; zbuf ; c ; ctl counters
__global__ void init_k(const float* __restrict__ h0, const float* __restrict__ c0,
                       unsigned short* hX, unsigned short* zbuf,
                       float* c0f, float* c1f, unsigned* ctl) {
  int i = blockIdx.x * blockDim.x + threadIdx.x;
  if (i < BH) {
    const int e = i & 7, lane = (i >> 3) & 63, kblk = (i >> 9) & 63, mtile = i >> 15;
    const int m = mtile * 16 + (lane & 15);
    const int k = kblk * 32 + ((lane >> 4) << 3) + e;
    const unsigned short v0 = f2bf(h0[m * HID + k]);
    const unsigned short v1 = f2bf(h0[BH + m * HID + k]);
#pragma unroll
    for (int x = 0; x < 8; ++x) {
      hX[(size_t)x * 131072 + i] = v0;
      hX[(size_t)x * 131072 + 65536 + i] = v1;
    }
    zbuf[i] = 0;
    c0f[i] = c0[i];
    c1f[i] = c0[BH + i];
  }
  if (i < 832) ctl[i] = 0u;
}

// ---------------- phase sync: gbar -> copy hG->X[xcd] -> local bar ---------
// ctl layout (u32): [g*32] g<8 gbar groups | [256] master | [288] epoch
//                   [320+x*32] lbar | [576+x*32] elect
__device__ __forceinline__ void phase_sync(unsigned* ctl, int bno, int lbno, int xcc,
                                           int role, int n_x, int n_c, int w, int lane,
                                           const unsigned short* hGm,
                                           unsigned short* Xm) {
  asm volatile("s_waitcnt vmcnt(0)" ::: "memory");
  __syncthreads();
  if (threadIdx.x == 0) {
    const int g = blockIdx.x >> 5;
    unsigned a = AT_ADD(&ctl[g * 32], 1u);
    if (a == (unsigned)(32 * bno - 1)) {
      unsigned m = AT_ADD(&ctl[256], 1u);
      if (m == (unsigned)(8 * bno - 1)) AT_ST(&ctl[288], (unsigned)bno);
    }
    while (AT_LD(&ctl[288]) < (unsigned)bno) __builtin_amdgcn_s_sleep(1);
  }
  __syncthreads();
  asm volatile("buffer_inv" ::: "memory");   // L1-only invalidate
  // copiers: hG (L3, sc0sc1 loads) -> X[xcd] (normal stores -> own-XCD L2)
  if (role < n_c) {
    for (int c = role * 8 + w; c < 128; c += n_c * 8) {
      const unsigned short* s = hGm + c * 512 + lane * 8;
      u32x4 v;
      asm volatile("global_load_dwordx4 %0, %1, off sc0 sc1"
                   : "=v"(v) : "v"((unsigned long long)(size_t)s) : "memory");
      asm volatile("s_waitcnt vmcnt(0)" ::: "memory");
      *(u32x4*)(Xm + c * 512 + lane * 8) = v;
    }
  }
  asm volatile("s_waitcnt vmcnt(0)" ::: "memory");
  __syncthreads();
  if (threadIdx.x == 0) {
    AT_ADD(&ctl[320 + xcc * 32], 1u);
    while (AT_LD(&ctl[320 + xcc * 32]) < (unsigned)(n_x * lbno))
      __builtin_amdgcn_s_sleep(1);
  }
  __syncthreads();
  asm volatile("buffer_inv" ::: "memory");   // fresh L1 view of X
}

#define PHASE_BODY(VARR, NV2, LBASE, CBUF, HOUTP, OUTP, BSEL)                     \
  {                                                                               \
    const short8* pa0 = (const short8*)Asrc + (size_t)(ks * 16) * 64 + lane;      \
    const short8* pa1 = pa0 + (size_t)64 * 64;                                    \
    f32x4 acc00 = {0.f, 0.f, 0.f, 0.f}, acc01 = acc00, acc10 = acc00, acc11 = acc00; \
    _Pragma("unroll")                                                             \
    for (int kk = 0; kk < NV2; ++kk) {                                            \
      short8 a0 = pa0[kk * 64], a1 = pa1[kk * 64];                                \
      short8 b0 = VARR[kk], b1 = VARR[16 + kk];                                   \
      acc00 = MFMA16(a0, b0, acc00); acc01 = MFMA16(a1, b0, acc01);               \
      acc10 = MFMA16(a0, b1, acc10); acc11 = MFMA16(a1, b1, acc11);               \
    }                                                                             \
    _Pragma("unroll")                                                             \
    for (int kk = NV2; kk < 16; ++kk) {                                           \
      short8 a0 = pa0[kk * 64], a1 = pa1[kk * 64];                                \
      short8 b0 = VARR[kk];                                                       \
      short8 b1 = lw[(w * 17 + LBASE + (kk - NV2)) * 64 + lane];                  \
      acc00 = MFMA16(a0, b0, acc00); acc01 = MFMA16(a1, b0, acc01);               \
      acc10 = MFMA16(a0, b1, acc10); acc11 = MFMA16(a1, b1, acc11);               \
    }                                                                             \
    *(f32x4*)&red[((w * 2 + 0) * 64 + lane) * 4] = acc00;                         \
    *(f32x4*)&red[((w * 2 + 1) * 64 + lane) * 4] = acc01;                         \
    __syncthreads();                                                              \
    float gi = 0.f, gf_ = 0.f;                                                    \
    if (tid < 256) {                                                              \
      const int b = tid >> 3, cc = tid & 7, m = b >> 4, br = b & 15;              \
      const int reg = br & 3, lb = (br >> 2) << 4;                                \
      _Pragma("unroll")                                                           \
      for (int ww = 0; ww < 8; ++ww) {                                            \
        gi  += red[((ww * 2 + m) * 64 + lb + cc) * 4 + reg];                      \
        gf_ += red[((ww * 2 + m) * 64 + lb + cc + 8) * 4 + reg];                  \
      }                                                                           \
    }                                                                             \
    __syncthreads();                                                              \
    *(f32x4*)&red[((w * 2 + 0) * 64 + lane) * 4] = acc10;                         \
    *(f32x4*)&red[((w * 2 + 1) * 64 + lane) * 4] = acc11;                         \
    __syncthreads();                                                              \
    if (tid < 256) {                                                              \
      const int b = tid >> 3, cc = tid & 7, m = b >> 4, br = b & 15;              \
      const int reg = br & 3, lb = (br >> 2) << 4;                                \
      float gg = 0.f, go = 0.f;                                                   \
      _Pragma("unroll")                                                           \
      for (int ww = 0; ww < 8; ++ww) {                                            \
        gg += red[((ww * 2 + m) * 64 + lb + cc) * 4 + reg];                       \
        go += red[((ww * 2 + m) * 64 + lb + cc + 8) * 4 + reg];                   \
      }                                                                           \
      const int col = wg * 8 + cc;                                                \
      gi  += (BSEL)[col];                                                         \
      gf_ += (BSEL)[2048 + col];                                                  \
      gg  += (BSEL)[4096 + col];                                                  \
      go  += (BSEL)[6144 + col];                                                  \
      const float iv = sigm(gi), fv = sigm(gf_), gv = tanh_(gg), ov = sigm(go);   \
      const float cold = (CBUF)[b * HID + col];                                   \
      const float cnew = fv * cold + iv * gv;                                     \
      const float hnew = ov * tanh_(cnew);                                        \
      (CBUF)[b * HID + col] = cnew;                                               \
      const int kblk = col >> 5, lh = (col >> 3) & 3, e = col & 7;                \
      const int lane_p = (b & 15) | (lh << 4), mt = b >> 4;                       \
      const unsigned hv = (unsigned)f2bf(hnew);                                   \
      unsigned long long ha = (unsigned long long)(size_t)                        \
          ((HOUTP) + ((size_t)(mt * 64 + kblk) * 64 + lane_p) * 8 + e);           \
      asm volatile("global_store_short %0, %1, off sc0 sc1"                       \
                   :: "v"(ha), "v"(hv) : "memory");                               \
      if (OUTP) ((float*)(OUTP))[b * HID + col] = hnew;                           \
    }                                                                             \
  }

__global__ __launch_bounds__(NTHR, 1) void lstm_persist(
    const unsigned short* __restrict__ Wfp, const unsigned short* __restrict__ Wh0p,
    const unsigned short* __restrict__ Wi1p, const unsigned short* __restrict__ Wh1p,
    const float* __restrict__ bA0, const float* __restrict__ bAf,
    const float* __restrict__ bB,
    unsigned short* hX,      // [8][2][65536] per-XCD cached copies
    unsigned short* hG,      // [2][65536] device-coherent staging
    const unsigned short* zbuf,
    float* c0f, float* c1f, float* __restrict__ out, int T, unsigned* ctl) {
  extern __shared__ __align__(16) char smem[];
  short8* lw = (short8*)smem;
  float* red = (float*)(smem + LDS_RED_OFF);
  const int wg = blockIdx.x, tid = threadIdx.x;
  const int w = tid >> 6, lane = tid & 63, ks = w & 3;
  const int xcc = (int)(__builtin_amdgcn_s_getreg((20) | (0 << 6) | (31 << 11)) & 7);
  const unsigned short* M0 = (w < 4) ? Wfp : Wh0p;
  const unsigned short* M1 = (w < 4) ? Wi1p : Wh1p;

  // election (physical-XCD role assignment)
  if (tid == 0) *(int*)red = (int)AT_ADD(&ctl[576 + xcc * 32], 1u);

  // weight prologue: 47 reg chunks + 17 LDS chunks per wave
  short8 v0[24], v1[23];
  {
    const short8* m0c = (const short8*)M0;
    const short8* m1c = (const short8*)M1;
#pragma unroll
    for (int c = 0; c < 24; ++c)
      v0[c] = m0c[(((size_t)(wg * 2 + (c >> 4)) * 64) + ks * 16 + (c & 15)) * 64 + lane];
#pragma unroll
    for (int c = 24; c < 32; ++c)
      lw[(w * 17 + (c - 24)) * 64 + lane] =
          m0c[(((size_t)(wg * 2 + (c >> 4)) * 64) + ks * 16 + (c & 15)) * 64 + lane];
#pragma unroll
    for (int c = 0; c < 23; ++c)
      v1[c] = m1c[(((size_t)(wg * 2 + (c >> 4)) * 64) + ks * 16 + (c & 15)) * 64 + lane];
#pragma unroll
    for (int c = 23; c < 32; ++c)
      lw[(w * 17 + 8 + (c - 23)) * 64 + lane] =
          m1c[(((size_t)(wg * 2 + (c >> 4)) * 64) + ks * 16 + (c & 15)) * 64 + lane];
  }
  __syncthreads();
  const int role = *(int*)red;
  unsigned short* Xh0 = hX + (size_t)xcc * 131072;
  unsigned short* Xh1 = Xh0 + 65536;

  // gbar #1: all elections done, weights loaded
  asm volatile("s_waitcnt vmcnt(0)" ::: "memory");
  __syncthreads();
  if (tid == 0) {
    const int g = blockIdx.x >> 5;
    unsigned a = AT_ADD(&ctl[g * 32], 1u);
    if (a == 31u) {
      unsigned m = AT_ADD(&ctl[256], 1u);
      if (m == 7u) AT_ST(&ctl[288], 1u);
    }
    while (AT_LD(&ctl[288]) < 1u) __builtin_amdgcn_s_sleep(1);
    *(int*)red = (int)AT_LD(&ctl[576 + xcc * 32]);
  }
  __syncthreads();
  const int n_x = *(int*)red;
  const int n_c = n_x < 16 ? n_x : 16;
  __syncthreads();

  int bno = 2, lbno = 1;
  for (int t = 0; t < T; ++t) {
    {  // phase A: gates0 = Wfused*h1(t-1) + Whh0*h0(t-1) -> h0(t), c0
      const unsigned short* Asrc = (w < 4) ? ((t == 0) ? zbuf : Xh1) : Xh0;
      const float* bsel = (t == 0) ? bA0 : bAf;
      PHASE_BODY(v0, 8, 0, c0f, hG, (float*)nullptr, bsel)
    }
    phase_sync(ctl, bno++, lbno++, xcc, role, n_x, n_c, w, lane, hG, Xh0);
    {  // phase B: gates1 = Wih1*h0(t) + Whh1*h1(t-1) -> h1(t), c1, out(t)
      const unsigned short* Asrc = (w < 4) ? Xh0 : Xh1;
      PHASE_BODY(v1, 7, 8, c1f, hG + 65536, out + (size_t)t * BH, bB)
    }
    phase_sync(ctl, bno++, lbno++, xcc, role, n_x, n_c, w, lane, hG + 65536, Xh1);
  }
}

extern "C" void kernel_launch(void* const* d_in, const int* in_sizes, int n_in,
                              void* d_out, int out_size, void* d_ws, size_t ws_size,
                              hipStream_t stream) {
  const float* h0 = (const float*)d_in[0];
  const float* c0 = (const float*)d_in[1];
  const float* Wih = (const float*)d_in[2];
  const float* Whh = (const float*)d_in[3];
  const float* bih = (const float*)d_in[4];
  const float* bhh = (const float*)d_in[5];
  const float* Wout = (const float*)d_in[6];
  const float* bout = (const float*)d_in[7];
  float* out = (float*)d_out;
  const int T = out_size / BH;

  unsigned short* Wfp = (unsigned short*)d_ws;
  unsigned short* Wh0p = Wfp + WMAT;
  unsigned short* Wi1p = Wfp + 2 * WMAT;
  unsigned short* Wh1p = Wfp + 3 * WMAT;
  unsigned short* tmpA = Wi1p;    // alias, dead after gemm_pack_k
  unsigned short* WoutT = Wh1p;   // alias, dead after gemm_pack_k
  unsigned short* S = Wfp + 4 * WMAT;
  unsigned short* hX = S;                    // 8*2*65536 = 1,048,576
  unsigned short* hG = S + 1048576;          // 2*65536
  unsigned short* zbuf = S + 1179648;        // 65536
  float* F = (float*)(S + 1245184);
  float* c0f = F;
  float* c1f = F + 65536;
  float* bA0 = F + 131072;
  float* bAf = F + 139264;
  float* bB = F + 147456;
  unsigned* ctl = (unsigned*)(F + 155648);   // 832 u32

  cvt_bf16_k<<<2048, 256, 0, stream>>>(Wih, tmpA, (long)(WMAT / 4));
  tcvt_k<<<dim3(32, 32), 256, 0, stream>>>(Wout, WoutT);
  gemm_pack_k<<<dim3(64, 16), 256, 0, stream>>>(tmpA, WoutT, Wfp);
  pack_W1_k<<<512, 256, 0, stream>>>(Whh, Wh0p);
  pack_W1_k<<<512, 256, 0, stream>>>(Wih + WMAT, Wi1p);
  pack_W1_k<<<512, 256, 0, stream>>>(Whh + WMAT, Wh1p);
  bias_k<<<1024, 512, 0, stream>>>(Wih, bout, bih, bhh, bA0, bAf, bB);
  init_k<<<256, 256, 0, stream>>>(h0, c0, hX, zbuf, c0f, c1f, ctl);

  (void)hipFuncSetAttribute((const void*)lstm_persist,
                            hipFuncAttributeMaxDynamicSharedMemorySize, LDS_BYTES);
  lstm_persist<<<NWG, NTHR, LDS_BYTES, stream>>>(Wfp, Wh0p, Wi1p, Wh1p,
                                                 bA0, bAf, bB,
                                                 hX, hG, zbuf, c0f, c1f, out, T, ctl);
}